// Round 11
// baseline (235.270 us; speedup 1.0000x reference)
//
#include <hip/hip_runtime.h>

typedef __bf16 bf16x8 __attribute__((ext_vector_type(8)));
typedef float  f32x4  __attribute__((ext_vector_type(4)));

// ---------- helpers ----------
__device__ __forceinline__ float bf2f(unsigned short h) {
    return __uint_as_float(((unsigned int)h) << 16);
}
__device__ __forceinline__ unsigned short f2bf(float f) {
    unsigned int u = __float_as_uint(f);
    u += 0x7FFFu + ((u >> 16) & 1u);  // RNE
    return (unsigned short)(u >> 16);
}
__device__ __forceinline__ void unpack8(uint4 u, float* v) {
    v[0] = __uint_as_float(u.x << 16); v[1] = __uint_as_float(u.x & 0xFFFF0000u);
    v[2] = __uint_as_float(u.y << 16); v[3] = __uint_as_float(u.y & 0xFFFF0000u);
    v[4] = __uint_as_float(u.z << 16); v[5] = __uint_as_float(u.z & 0xFFFF0000u);
    v[6] = __uint_as_float(u.w << 16); v[7] = __uint_as_float(u.w & 0xFFFF0000u);
}

// ---------- K1: deg_rank (blocks < degBlocks) || detect (last block) ----------
__global__ void k1_deg_detect(const int* __restrict__ dst, int* __restrict__ deg,
                              int* __restrict__ rank, int E,
                              const unsigned short* __restrict__ x, int* __restrict__ cnt,
                              int degBlocks) {
    if ((int)blockIdx.x < degBlocks) {
        int base = blockIdx.x * 1024 + threadIdx.x;
#pragma unroll
        for (int k = 0; k < 4; ++k) {
            int e = base + k * 256;
            if (e < E) rank[e] = atomicAdd(&deg[dst[e]], 1);
        }
    } else {
        int c = 0;
        for (int i = threadIdx.x; i < 4096; i += 256) {
            unsigned e = (x[i] >> 7) & 0xFFu;
            if (e >= 0x88u) ++c;  // impossible for bf16 N(0,1); ~47% for fp32 low halves
        }
        if (c) atomicAdd(cnt, c);
    }
}

// ---------- weight prepack device fn ----------
// Wp[((nt*4 + ks)*64 + lane)*8 + j] = W[ks*32 + (lane>>4)*8 + j][nt*16 + (lane&15)]
template <int COLS>
__device__ __forceinline__ void prepack_one(const void* W, unsigned short* Wp, int idx,
                                            bool isf32) {
    if (idx >= (COLS / 16) * 4 * 64) return;
    int lane = idx & 63;
    int ks   = (idx >> 6) & 3;
    int nt   = idx >> 8;
    int col  = nt * 16 + (lane & 15);
    int krow = ks * 32 + (lane >> 4) * 8;
    unsigned short tmp[8];
#pragma unroll
    for (int j = 0; j < 8; ++j) {
        size_t e = (size_t)(krow + j) * COLS + col;
        float v = isf32 ? ((const float*)W)[e] : bf2f(((const unsigned short*)W)[e]);
        tmp[j] = f2bf(v);
    }
    *(uint4*)(Wp + (size_t)idx * 8) = *(uint4*)tmp;
}

// ---------- K2: scan1+dinv (blocks < NB) || prep_weights (blocks NB..NB+12) ----------
__global__ void k2_scan1_prep(const int* __restrict__ deg, int* __restrict__ offs,
                              int* __restrict__ bsum, float* __restrict__ dinv, int N, int NB,
                              const void* __restrict__ W1, const void* __restrict__ W2,
                              const void* __restrict__ b1, const void* __restrict__ b2,
                              unsigned short* __restrict__ Wp1, unsigned short* __restrict__ Wp2,
                              float* __restrict__ b1f, float* __restrict__ b2f,
                              const int* __restrict__ cnt) {
    __shared__ int s[256];
    int t = threadIdx.x;
    if ((int)blockIdx.x < NB) {
        int base = blockIdx.x * 1024 + t * 4;
        int d4[4];
#pragma unroll
        for (int k = 0; k < 4; ++k) d4[k] = (base + k < N) ? deg[base + k] : 0;
#pragma unroll
        for (int k = 0; k < 4; ++k)
            if (base + k < N) dinv[base + k] = rsqrtf((float)d4[k] + 1.0f);  // +1 self loop
        int mySum = d4[0] + d4[1] + d4[2] + d4[3];
        s[t] = mySum;
        __syncthreads();
        for (int d = 1; d < 256; d <<= 1) {
            int v = (t >= d) ? s[t - d] : 0;
            __syncthreads();
            s[t] += v;
            __syncthreads();
        }
        int run = s[t] - mySum;  // exclusive within block
#pragma unroll
        for (int k = 0; k < 4; ++k) {
            if (base + k < N) offs[base + k] = run;
            run += d4[k];
        }
        if (t == 255) bsum[blockIdx.x] = s[255];
    } else {
        bool isf32 = (*cnt >= 16);
        int bid = blockIdx.x - NB;
        if (bid < 8) {
            prepack_one<128>(W1, Wp1, bid * 256 + t, isf32);
        } else if (bid < 12) {
            prepack_one<64>(W2, Wp2, (bid - 8) * 256 + t, isf32);
        } else {
            if (t < 128) b1f[t] = isf32 ? ((const float*)b1)[t]
                                        : bf2f(((const unsigned short*)b1)[t]);
            else if (t < 192) b2f[t - 128] = isf32 ? ((const float*)b2)[t - 128]
                                                   : bf2f(((const unsigned short*)b2)[t - 128]);
        }
    }
}

// ---------- K3: scan2 recomputed per block + scan3 apply (needs NB <= 256) ----------
__global__ void scan23(const int* __restrict__ bsum, int* __restrict__ offs,
                       int N, int E, int NB) {
    __shared__ int s[256];
    int t = threadIdx.x;
    s[t] = (t < NB) ? bsum[t] : 0;
    __syncthreads();
    for (int d = 1; d < 256; d <<= 1) {
        int v = (t >= d) ? s[t - d] : 0;
        __syncthreads();
        s[t] += v;
        __syncthreads();
    }
    int boff = (blockIdx.x > 0) ? s[blockIdx.x - 1] : 0;  // exclusive prefix
    int base = blockIdx.x * 1024 + t * 4;
#pragma unroll
    for (int k = 0; k < 4; ++k) {
        int i = base + k;
        if (i < N) offs[i] += boff;
    }
    if (blockIdx.x == 0 && t == 0) offs[N] = E;
}

// ---------- MFMA GEMM body with dinv-pre-scaled epilogue ----------
// O[row] = bf16( (X@W)[row] * dinv[row] )
// A: m=lane&15, k=(lane>>4)*8+j. C/D: col=lane&15, row=(lane>>4)*4+reg.
template <int COLS, int XMODE>
__device__ __forceinline__ void gemm_body(const void* __restrict__ X,
                                          const unsigned short* __restrict__ Wp,
                                          const float* __restrict__ dinv,
                                          unsigned short* __restrict__ O, int nstrips,
                                          bool xf32f, int blockI) {
    constexpr int NT = COLS / 16;
    const int wave = threadIdx.x >> 6;
    const int lane = threadIdx.x & 63;
    const int strip = blockI * 4 + wave;
    if (strip >= nstrips) return;
    const bool xf32 = (XMODE == 0) && xf32f;
    const int m = lane & 15;
    const int q = lane >> 4;
    const size_t rowoff = (size_t)(strip * 16 + m) * 128 + q * 8;

    f32x4 acc[NT];
#pragma unroll
    for (int nt = 0; nt < NT; ++nt) acc[nt] = (f32x4){0.f, 0.f, 0.f, 0.f};

#pragma unroll
    for (int ks = 0; ks < 4; ++ks) {
        bf16x8 a;
        if (xf32) {
            const float* xp = (const float*)X + rowoff + ks * 32;
            float4 u = ((const float4*)xp)[0];
            float4 v = ((const float4*)xp)[1];
            unsigned short tmp[8];
            tmp[0] = f2bf(u.x); tmp[1] = f2bf(u.y); tmp[2] = f2bf(u.z); tmp[3] = f2bf(u.w);
            tmp[4] = f2bf(v.x); tmp[5] = f2bf(v.y); tmp[6] = f2bf(v.z); tmp[7] = f2bf(v.w);
            a = *(bf16x8*)tmp;
        } else {
            a = *(const bf16x8*)((const unsigned short*)X + rowoff + ks * 32);
        }
#pragma unroll
        for (int nt = 0; nt < NT; ++nt) {
            bf16x8 b = *(const bf16x8*)(Wp + (size_t)((nt * 4 + ks) * 64 + lane) * 8);
            acc[nt] = __builtin_amdgcn_mfma_f32_16x16x32_bf16(a, b, acc[nt], 0, 0, 0);
        }
    }

    const int r0 = strip * 16 + q * 4;             // multiple of 4
    float4 dv = *(const float4*)(dinv + r0);       // dinv for my 4 output rows
    float dr[4] = {dv.x, dv.y, dv.z, dv.w};
#pragma unroll
    for (int nt = 0; nt < NT; ++nt) {
#pragma unroll
        for (int r = 0; r < 4; ++r)
            O[(size_t)(r0 + r) * COLS + nt * 16 + m] = f2bf(acc[nt][r] * dr[r]);
    }
}

// ---------- K5: atomic-free scatter (blocks < EB) || gemm1 ----------
__global__ __launch_bounds__(256) void k5_scatter_gemm1(
        const int* __restrict__ src, const int* __restrict__ dst,
        const int* __restrict__ offs, const int* __restrict__ rank,
        int* __restrict__ adj, int E, int EB,
        const void* __restrict__ X, const unsigned short* __restrict__ Wp,
        const float* __restrict__ dinv,
        unsigned short* __restrict__ O, int nstrips, const int* __restrict__ cnt) {
    if ((int)blockIdx.x < EB) {
        int base = blockIdx.x * 1024 + threadIdx.x;
#pragma unroll
        for (int k = 0; k < 4; ++k) {
            int e = base + k * 256;
            if (e < E) adj[offs[dst[e]] + rank[e]] = src[e];
        }
    } else {
        gemm_body<128, 0>(X, Wp, dinv, O, nstrips, (*cnt >= 16), blockIdx.x - EB);
    }
}

// ---------- gemm2 standalone ----------
__global__ __launch_bounds__(256) void gemm2_k(const void* __restrict__ X,
                                               const unsigned short* __restrict__ Wp,
                                               const float* __restrict__ dinv,
                                               unsigned short* __restrict__ O, int nstrips) {
    gemm_body<64, 1>(X, Wp, dinv, O, nstrips, false, blockIdx.x);
}

// ---------- gather layer 1: R1 = relu(dd*(sum Hb'[s] + Hb'[nd]) + b) ----------
// One node per WAVE: 4 groups x 16 lanes all on the same node's edges (group g takes
// 16-edge chunks at beg+g*16, stride 64), butterfly-reduce via shfl_xor(16,32).
// Hb' is pre-scaled by dinv (GEMM epilogue) -> no per-edge dinv load.
__global__ void gather1(const unsigned short* __restrict__ Hb, const float* __restrict__ dinv,
                        const float* __restrict__ b, const int* __restrict__ offs,
                        const int* __restrict__ adj, unsigned short* __restrict__ R1,
                        int N) {
    int nd = blockIdx.x * 4 + (threadIdx.x >> 6);
    if (nd >= N) return;
    int lane = threadIdx.x & 63;
    int g = lane >> 4;          // group 0..3
    int l15 = lane & 15;
    int gbase = lane & ~15;
    int f8 = l15 * 8;

    float acc[8];
#pragma unroll
    for (int k = 0; k < 8; ++k) acc[k] = 0.f;

    int beg = offs[nd], end = offs[nd + 1];
    for (int c = beg + g * 16; c < end; c += 64) {
        int cnt16 = end - c; if (cnt16 > 16) cnt16 = 16;
        int myadj = (l15 < cnt16) ? adj[c + l15] : 0;  // dummy idx 0, weight 0
#pragma unroll
        for (int t = 0; t < 16; t += 8) {
            if (t >= cnt16) break;
            int sI[8];
#pragma unroll
            for (int k = 0; k < 8; ++k) sI[k] = __shfl(myadj, gbase + t + k, 64);
            uint4 u[8];
#pragma unroll
            for (int k = 0; k < 8; ++k) u[k] = *(const uint4*)(Hb + (size_t)sI[k] * 128 + f8);
            float n[8];
#pragma unroll
            for (int k = 0; k < 8; ++k) n[k] = (t + k < cnt16) ? 1.f : 0.f;
#pragma unroll
            for (int k = 0; k < 8; ++k) {
                float v[8];
                unpack8(u[k], v);
#pragma unroll
                for (int j = 0; j < 8; ++j) acc[j] = fmaf(v[j], n[k], acc[j]);
            }
        }
    }
    // reduce across the 4 groups
#pragma unroll
    for (int k = 0; k < 8; ++k) {
        acc[k] += __shfl_xor(acc[k], 16, 64);
        acc[k] += __shfl_xor(acc[k], 32, 64);
    }
    if (g == 0) {
        float dd = dinv[nd];
        float hv[8], bb[8];
        unpack8(*(const uint4*)(Hb + (size_t)nd * 128 + f8), hv);  // self (pre-scaled)
        *(float4*)&bb[0] = *(const float4*)(b + f8);
        *(float4*)&bb[4] = *(const float4*)(b + f8 + 4);
        unsigned short o[8];
#pragma unroll
        for (int k = 0; k < 8; ++k) {
            float a = fmaf(acc[k] + hv[k], dd, bb[k]);
            o[k] = f2bf(fmaxf(a, 0.f));
        }
        *(uint4*)(R1 + (size_t)nd * 128 + f8) = *(uint4*)o;
    }
}

// ---------- gather layer 2: out = dd*(sum H2b'[s] + H2b'[nd]) + b ----------
// One node per WAVE: 8 groups x 8 lanes, shfl_xor(8,16,32) reduce.
__global__ void gather2(const unsigned short* __restrict__ H2b, const float* __restrict__ dinv,
                        const float* __restrict__ b, const int* __restrict__ offs,
                        const int* __restrict__ adj, void* __restrict__ out,
                        int N, const int* __restrict__ cnt) {
    int nd = blockIdx.x * 4 + (threadIdx.x >> 6);
    if (nd >= N) return;
    bool isf32 = (*cnt >= 16);
    int lane = threadIdx.x & 63;
    int g = lane >> 3;          // group 0..7
    int l7 = lane & 7;
    int gbase = lane & ~7;
    int f8 = l7 * 8;

    float acc[8];
#pragma unroll
    for (int k = 0; k < 8; ++k) acc[k] = 0.f;

    int beg = offs[nd], end = offs[nd + 1];
    for (int c = beg + g * 8; c < end; c += 64) {
        int cnt8 = end - c; if (cnt8 > 8) cnt8 = 8;
        int myadj = (l7 < cnt8) ? adj[c + l7] : 0;
        int sI[8];
#pragma unroll
        for (int k = 0; k < 8; ++k) sI[k] = __shfl(myadj, gbase + k, 64);
        uint4 u[8];
#pragma unroll
        for (int k = 0; k < 8; ++k) u[k] = *(const uint4*)(H2b + (size_t)sI[k] * 64 + f8);
        float n[8];
#pragma unroll
        for (int k = 0; k < 8; ++k) n[k] = (k < cnt8) ? 1.f : 0.f;
#pragma unroll
        for (int k = 0; k < 8; ++k) {
            float v[8];
            unpack8(u[k], v);
#pragma unroll
            for (int j = 0; j < 8; ++j) acc[j] = fmaf(v[j], n[k], acc[j]);
        }
    }
#pragma unroll
    for (int k = 0; k < 8; ++k) {
        acc[k] += __shfl_xor(acc[k], 8, 64);
        acc[k] += __shfl_xor(acc[k], 16, 64);
        acc[k] += __shfl_xor(acc[k], 32, 64);
    }
    if (g == 0) {
        float dd = dinv[nd];
        float hv[8], bb[8];
        unpack8(*(const uint4*)(H2b + (size_t)nd * 64 + f8), hv);
        *(float4*)&bb[0] = *(const float4*)(b + f8);
        *(float4*)&bb[4] = *(const float4*)(b + f8 + 4);
        float r[8];
#pragma unroll
        for (int k = 0; k < 8; ++k) r[k] = fmaf(acc[k] + hv[k], dd, bb[k]);
        if (isf32) {
            float* op = (float*)out + (size_t)nd * 64 + f8;
            *(float4*)op       = *(float4*)&r[0];
            *(float4*)(op + 4) = *(float4*)&r[4];
        } else {
            unsigned short o[8];
#pragma unroll
            for (int k = 0; k < 8; ++k) o[k] = f2bf(r[k]);
            *(uint4*)((unsigned short*)out + (size_t)nd * 64 + f8) = *(uint4*)o;
        }
    }
}

extern "C" void kernel_launch(void* const* d_in, const int* in_sizes, int n_in,
                              void* d_out, int out_size, void* d_ws, size_t ws_size,
                              hipStream_t stream) {
    const void* x  = d_in[0];                        // [N][128] fp32 (or bf16)
    const int*  ei = (const int*)d_in[1];            // [2][E] int32
    const void* W1 = d_in[2];                        // [128][128]
    const void* b1 = d_in[3];                        // [128]
    const void* W2 = d_in[4];                        // [128][64]
    const void* b2 = d_in[5];                        // [64]

    const int N = in_sizes[0] / 128;
    const int E = in_sizes[1] / 2;
    const int* src = ei;
    const int* dst = ei + E;

    // bump allocator over ws (float units, 64B-aligned slots)
    float* ws = (float*)d_ws;
    size_t off = 0;
    auto alloc = [&](size_t n) { size_t p = off; off += (n + 15) & ~(size_t)15; return p; };
    int*   cnt    = (int*)(ws + alloc(64));
    int*   deg    = (int*)(ws + alloc(N));
    float* dinv   = ws + alloc(N);
    int*   offs   = (int*)(ws + alloc(N + 1));
    int*   bsum   = (int*)(ws + alloc(256));
    int*   adj    = (int*)(ws + alloc(E));
    int*   rank   = (int*)(ws + alloc(E));
    unsigned short* R1  = (unsigned short*)(ws + alloc((size_t)N * 64));  // bf16 [N][128]
    unsigned short* Hb  = (unsigned short*)(ws + alloc((size_t)N * 64));  // bf16 [N][128]
    unsigned short* Wp1 = (unsigned short*)(ws + alloc(8192));            // 16384 bf16
    unsigned short* Wp2 = (unsigned short*)(ws + alloc(4096));            // 8192 bf16
    float* b1f    = ws + alloc(128);
    float* b2f    = ws + alloc(64);
    unsigned short* H2b = Hb;  // bf16 [N][64]; Hb dead after gather1

    // zero cnt + deg (contiguous leading region)
    hipMemsetAsync(ws, 0, (64 + ((size_t)(N + 15) & ~(size_t)15)) * sizeof(float), stream);

    const int EB = (E + 1023) / 1024;   // deg_rank / scatter blocks
    const int NB = (N + 1023) / 1024;   // scan blocks (49 <= 256 required by scan23)
    const int nstrips = (N + 15) / 16;  // 3125
    const int GB = (nstrips + 3) / 4;   // gemm blocks

    // K1: degree+rank || dtype detect
    k1_deg_detect<<<EB + 1, 256, 0, stream>>>(dst, deg, rank, E,
                                              (const unsigned short*)x, cnt, EB);
    // K2: scan1(+dinv) || weight/bias prep
    k2_scan1_prep<<<NB + 13, 256, 0, stream>>>(deg, offs, bsum, dinv, N, NB,
                                               W1, W2, b1, b2, Wp1, Wp2, b1f, b2f, cnt);
    // K3: block-prefix + apply
    scan23<<<NB, 256, 0, stream>>>(bsum, offs, N, E, NB);
    // K5: edge scatter (first: longer pole) || layer-1 GEMM (dinv-scaled epilogue)
    k5_scatter_gemm1<<<EB + GB, 256, 0, stream>>>(src, dst, offs, rank, adj, E, EB,
                                                  x, Wp1, dinv, Hb, nstrips, cnt);
    // gather 1 (one node/wave, relu, bf16)
    gather1<<<(N + 3) / 4, 256, 0, stream>>>(Hb, dinv, b1f, offs, adj, R1, N);
    // layer-2 GEMM (dinv-scaled epilogue)
    gemm2_k<<<GB, 256, 0, stream>>>(R1, Wp2, dinv, H2b, nstrips);
    // gather 2 -> output
    gather2<<<(N + 3) / 4, 256, 0, stream>>>(H2b, dinv, b2f, offs, adj, d_out, N, cnt);
}

// Round 12
// 195.987 us; speedup vs baseline: 1.2004x; 1.2004x over previous
//
#include <hip/hip_runtime.h>

typedef __bf16 bf16x8 __attribute__((ext_vector_type(8)));
typedef float  f32x4  __attribute__((ext_vector_type(4)));

// ---------- helpers ----------
__device__ __forceinline__ float bf2f(unsigned short h) {
    return __uint_as_float(((unsigned int)h) << 16);
}
__device__ __forceinline__ unsigned short f2bf(float f) {
    unsigned int u = __float_as_uint(f);
    u += 0x7FFFu + ((u >> 16) & 1u);  // RNE
    return (unsigned short)(u >> 16);
}
__device__ __forceinline__ void unpack8(uint4 u, float* v) {
    v[0] = __uint_as_float(u.x << 16); v[1] = __uint_as_float(u.x & 0xFFFF0000u);
    v[2] = __uint_as_float(u.y << 16); v[3] = __uint_as_float(u.y & 0xFFFF0000u);
    v[4] = __uint_as_float(u.z << 16); v[5] = __uint_as_float(u.z & 0xFFFF0000u);
    v[6] = __uint_as_float(u.w << 16); v[7] = __uint_as_float(u.w & 0xFFFF0000u);
}

// ---------- K1: deg_rank (blocks < degBlocks) || detect (last block) ----------
__global__ void k1_deg_detect(const int* __restrict__ dst, int* __restrict__ deg,
                              int* __restrict__ rank, int E,
                              const unsigned short* __restrict__ x, int* __restrict__ cnt,
                              int degBlocks) {
    if ((int)blockIdx.x < degBlocks) {
        int base = blockIdx.x * 1024 + threadIdx.x;
#pragma unroll
        for (int k = 0; k < 4; ++k) {
            int e = base + k * 256;
            if (e < E) rank[e] = atomicAdd(&deg[dst[e]], 1);
        }
    } else {
        int c = 0;
        for (int i = threadIdx.x; i < 4096; i += 256) {
            unsigned e = (x[i] >> 7) & 0xFFu;
            if (e >= 0x88u) ++c;  // impossible for bf16 N(0,1); ~47% for fp32 low halves
        }
        if (c) atomicAdd(cnt, c);
    }
}

// ---------- weight prepack device fn ----------
// Wp[((nt*4 + ks)*64 + lane)*8 + j] = W[ks*32 + (lane>>4)*8 + j][nt*16 + (lane&15)]
template <int COLS>
__device__ __forceinline__ void prepack_one(const void* W, unsigned short* Wp, int idx,
                                            bool isf32) {
    if (idx >= (COLS / 16) * 4 * 64) return;
    int lane = idx & 63;
    int ks   = (idx >> 6) & 3;
    int nt   = idx >> 8;
    int col  = nt * 16 + (lane & 15);
    int krow = ks * 32 + (lane >> 4) * 8;
    unsigned short tmp[8];
#pragma unroll
    for (int j = 0; j < 8; ++j) {
        size_t e = (size_t)(krow + j) * COLS + col;
        float v = isf32 ? ((const float*)W)[e] : bf2f(((const unsigned short*)W)[e]);
        tmp[j] = f2bf(v);
    }
    *(uint4*)(Wp + (size_t)idx * 8) = *(uint4*)tmp;
}

// ---------- K2: scan1+dinv (blocks < NB) || prep_weights (blocks NB..NB+12) ----------
__global__ void k2_scan1_prep(const int* __restrict__ deg, int* __restrict__ offs,
                              int* __restrict__ bsum, float* __restrict__ dinv, int N, int NB,
                              const void* __restrict__ W1, const void* __restrict__ W2,
                              const void* __restrict__ b1, const void* __restrict__ b2,
                              unsigned short* __restrict__ Wp1, unsigned short* __restrict__ Wp2,
                              float* __restrict__ b1f, float* __restrict__ b2f,
                              const int* __restrict__ cnt) {
    __shared__ int s[256];
    int t = threadIdx.x;
    if ((int)blockIdx.x < NB) {
        int base = blockIdx.x * 1024 + t * 4;
        int d4[4];
#pragma unroll
        for (int k = 0; k < 4; ++k) d4[k] = (base + k < N) ? deg[base + k] : 0;
#pragma unroll
        for (int k = 0; k < 4; ++k)
            if (base + k < N) dinv[base + k] = rsqrtf((float)d4[k] + 1.0f);  // +1 self loop
        int mySum = d4[0] + d4[1] + d4[2] + d4[3];
        s[t] = mySum;
        __syncthreads();
        for (int d = 1; d < 256; d <<= 1) {
            int v = (t >= d) ? s[t - d] : 0;
            __syncthreads();
            s[t] += v;
            __syncthreads();
        }
        int run = s[t] - mySum;  // exclusive within block
#pragma unroll
        for (int k = 0; k < 4; ++k) {
            if (base + k < N) offs[base + k] = run;
            run += d4[k];
        }
        if (t == 255) bsum[blockIdx.x] = s[255];
    } else {
        bool isf32 = (*cnt >= 16);
        int bid = blockIdx.x - NB;
        if (bid < 8) {
            prepack_one<128>(W1, Wp1, bid * 256 + t, isf32);
        } else if (bid < 12) {
            prepack_one<64>(W2, Wp2, (bid - 8) * 256 + t, isf32);
        } else {
            if (t < 128) b1f[t] = isf32 ? ((const float*)b1)[t]
                                        : bf2f(((const unsigned short*)b1)[t]);
            else if (t < 192) b2f[t - 128] = isf32 ? ((const float*)b2)[t - 128]
                                                   : bf2f(((const unsigned short*)b2)[t - 128]);
        }
    }
}

// ---------- K3: scan2 recomputed per block + scan3 apply (needs NB <= 256) ----------
__global__ void scan23(const int* __restrict__ bsum, int* __restrict__ offs,
                       int N, int E, int NB) {
    __shared__ int s[256];
    int t = threadIdx.x;
    s[t] = (t < NB) ? bsum[t] : 0;
    __syncthreads();
    for (int d = 1; d < 256; d <<= 1) {
        int v = (t >= d) ? s[t - d] : 0;
        __syncthreads();
        s[t] += v;
        __syncthreads();
    }
    int boff = (blockIdx.x > 0) ? s[blockIdx.x - 1] : 0;  // exclusive prefix
    int base = blockIdx.x * 1024 + t * 4;
#pragma unroll
    for (int k = 0; k < 4; ++k) {
        int i = base + k;
        if (i < N) offs[i] += boff;
    }
    if (blockIdx.x == 0 && t == 0) offs[N] = E;
}

// ---------- MFMA GEMM body with dinv-pre-scaled epilogue ----------
// O[row] = bf16( (X@W)[row] * dinv[row] )
// A: m=lane&15, k=(lane>>4)*8+j. C/D: col=lane&15, row=(lane>>4)*4+reg.
template <int COLS, int XMODE>
__device__ __forceinline__ void gemm_body(const void* __restrict__ X,
                                          const unsigned short* __restrict__ Wp,
                                          const float* __restrict__ dinv,
                                          unsigned short* __restrict__ O, int nstrips,
                                          bool xf32f, int blockI) {
    constexpr int NT = COLS / 16;
    const int wave = threadIdx.x >> 6;
    const int lane = threadIdx.x & 63;
    const int strip = blockI * 4 + wave;
    if (strip >= nstrips) return;
    const bool xf32 = (XMODE == 0) && xf32f;
    const int m = lane & 15;
    const int q = lane >> 4;
    const size_t rowoff = (size_t)(strip * 16 + m) * 128 + q * 8;

    f32x4 acc[NT];
#pragma unroll
    for (int nt = 0; nt < NT; ++nt) acc[nt] = (f32x4){0.f, 0.f, 0.f, 0.f};

#pragma unroll
    for (int ks = 0; ks < 4; ++ks) {
        bf16x8 a;
        if (xf32) {
            const float* xp = (const float*)X + rowoff + ks * 32;
            float4 u = ((const float4*)xp)[0];
            float4 v = ((const float4*)xp)[1];
            unsigned short tmp[8];
            tmp[0] = f2bf(u.x); tmp[1] = f2bf(u.y); tmp[2] = f2bf(u.z); tmp[3] = f2bf(u.w);
            tmp[4] = f2bf(v.x); tmp[5] = f2bf(v.y); tmp[6] = f2bf(v.z); tmp[7] = f2bf(v.w);
            a = *(bf16x8*)tmp;
        } else {
            a = *(const bf16x8*)((const unsigned short*)X + rowoff + ks * 32);
        }
#pragma unroll
        for (int nt = 0; nt < NT; ++nt) {
            bf16x8 b = *(const bf16x8*)(Wp + (size_t)((nt * 4 + ks) * 64 + lane) * 8);
            acc[nt] = __builtin_amdgcn_mfma_f32_16x16x32_bf16(a, b, acc[nt], 0, 0, 0);
        }
    }

    const int r0 = strip * 16 + q * 4;             // multiple of 4
    float4 dv = *(const float4*)(dinv + r0);       // dinv for my 4 output rows
    float dr[4] = {dv.x, dv.y, dv.z, dv.w};
#pragma unroll
    for (int nt = 0; nt < NT; ++nt) {
#pragma unroll
        for (int r = 0; r < 4; ++r)
            O[(size_t)(r0 + r) * COLS + nt * 16 + m] = f2bf(acc[nt][r] * dr[r]);
    }
}

// ---------- K5: atomic-free scatter (blocks < EB) || gemm1 ----------
__global__ __launch_bounds__(256) void k5_scatter_gemm1(
        const int* __restrict__ src, const int* __restrict__ dst,
        const int* __restrict__ offs, const int* __restrict__ rank,
        int* __restrict__ adj, int E, int EB,
        const void* __restrict__ X, const unsigned short* __restrict__ Wp,
        const float* __restrict__ dinv,
        unsigned short* __restrict__ O, int nstrips, const int* __restrict__ cnt) {
    if ((int)blockIdx.x < EB) {
        int base = blockIdx.x * 1024 + threadIdx.x;
#pragma unroll
        for (int k = 0; k < 4; ++k) {
            int e = base + k * 256;
            if (e < E) adj[offs[dst[e]] + rank[e]] = src[e];
        }
    } else {
        gemm_body<128, 0>(X, Wp, dinv, O, nstrips, (*cnt >= 16), blockIdx.x - EB);
    }
}

// ---------- gemm2 standalone ----------
__global__ __launch_bounds__(256) void gemm2_k(const void* __restrict__ X,
                                               const unsigned short* __restrict__ Wp,
                                               const float* __restrict__ dinv,
                                               unsigned short* __restrict__ O, int nstrips) {
    gemm_body<64, 1>(X, Wp, dinv, O, nstrips, false, blockIdx.x);
}

// ---------- gather layer 1: R1 = relu(dd*(sum Hb'[s] + Hb'[nd]) + b) ----------
// 16 lanes/node, 16 nodes/block; adj batched 16/chunk (coalesced + shfl); 8-way
// unrolled loads. Hb' pre-scaled by dinv -> edge weight is a 1/0 mask, no dinv[s] load.
__global__ void gather1(const unsigned short* __restrict__ Hb, const float* __restrict__ dinv,
                        const float* __restrict__ b, const int* __restrict__ offs,
                        const int* __restrict__ adj, unsigned short* __restrict__ R1,
                        int N) {
    int nd = blockIdx.x * 16 + (threadIdx.x >> 4);
    int lane = threadIdx.x & 63;
    int l15 = lane & 15;
    int gbase = lane & ~15;
    int f8 = l15 * 8;
    if (nd >= N) return;

    float acc[8];
#pragma unroll
    for (int k = 0; k < 8; ++k) acc[k] = 0.f;

    int beg = offs[nd], end = offs[nd + 1];
    for (int c = beg; c < end; c += 16) {
        int rem = end - c;  // >= 1
        int myadj = (l15 < rem) ? adj[c + l15] : 0;  // dummy row 0, weight 0
#pragma unroll
        for (int t = 0; t < 16; t += 8) {
            if (t >= rem) break;
            int sI[8];
#pragma unroll
            for (int k = 0; k < 8; ++k) sI[k] = __shfl(myadj, gbase + t + k, 64);
            uint4 u[8];
#pragma unroll
            for (int k = 0; k < 8; ++k) u[k] = *(const uint4*)(Hb + (size_t)sI[k] * 128 + f8);
            float n[8];
#pragma unroll
            for (int k = 0; k < 8; ++k) n[k] = (t + k < rem) ? 1.f : 0.f;
#pragma unroll
            for (int k = 0; k < 8; ++k) {
                float v[8];
                unpack8(u[k], v);
#pragma unroll
                for (int j = 0; j < 8; ++j) acc[j] = fmaf(v[j], n[k], acc[j]);
            }
        }
    }
    float dd = dinv[nd];
    float hv[8], bb[8];
    unpack8(*(const uint4*)(Hb + (size_t)nd * 128 + f8), hv);  // self (pre-scaled)
    *(float4*)&bb[0] = *(const float4*)(b + f8);
    *(float4*)&bb[4] = *(const float4*)(b + f8 + 4);
    unsigned short o[8];
#pragma unroll
    for (int k = 0; k < 8; ++k) {
        float a = fmaf(acc[k] + hv[k], dd, bb[k]);
        o[k] = f2bf(fmaxf(a, 0.f));
    }
    *(uint4*)(R1 + (size_t)nd * 128 + f8) = *(uint4*)o;
}

// ---------- gather layer 2: out = dd*(sum H2b'[s] + H2b'[nd]) + b ----------
// 8 lanes/node, 32 nodes/block; adj batched 8/chunk, straight-line 8-way body.
__global__ void gather2(const unsigned short* __restrict__ H2b, const float* __restrict__ dinv,
                        const float* __restrict__ b, const int* __restrict__ offs,
                        const int* __restrict__ adj, void* __restrict__ out,
                        int N, const int* __restrict__ cnt) {
    bool isf32 = (*cnt >= 16);
    int nd = blockIdx.x * 32 + (threadIdx.x >> 3);
    int lane = threadIdx.x & 63;
    int l7 = lane & 7;
    int gbase = lane & ~7;
    int f8 = l7 * 8;
    if (nd >= N) return;

    float acc[8];
#pragma unroll
    for (int k = 0; k < 8; ++k) acc[k] = 0.f;

    int beg = offs[nd], end = offs[nd + 1];
    for (int c = beg; c < end; c += 8) {
        int rem = end - c;
        int myadj = (l7 < rem) ? adj[c + l7] : 0;
        int sI[8];
#pragma unroll
        for (int k = 0; k < 8; ++k) sI[k] = __shfl(myadj, gbase + k, 64);
        uint4 u[8];
#pragma unroll
        for (int k = 0; k < 8; ++k) u[k] = *(const uint4*)(H2b + (size_t)sI[k] * 64 + f8);
        float n[8];
#pragma unroll
        for (int k = 0; k < 8; ++k) n[k] = (k < rem) ? 1.f : 0.f;
#pragma unroll
        for (int k = 0; k < 8; ++k) {
            float v[8];
            unpack8(u[k], v);
#pragma unroll
            for (int j = 0; j < 8; ++j) acc[j] = fmaf(v[j], n[k], acc[j]);
        }
    }
    float dd = dinv[nd];
    float hv[8], bb[8];
    unpack8(*(const uint4*)(H2b + (size_t)nd * 64 + f8), hv);
    *(float4*)&bb[0] = *(const float4*)(b + f8);
    *(float4*)&bb[4] = *(const float4*)(b + f8 + 4);
    float r[8];
#pragma unroll
    for (int k = 0; k < 8; ++k) r[k] = fmaf(acc[k] + hv[k], dd, bb[k]);
    if (isf32) {
        float* op = (float*)out + (size_t)nd * 64 + f8;
        *(float4*)op       = *(float4*)&r[0];
        *(float4*)(op + 4) = *(float4*)&r[4];
    } else {
        unsigned short o[8];
#pragma unroll
        for (int k = 0; k < 8; ++k) o[k] = f2bf(r[k]);
        *(uint4*)((unsigned short*)out + (size_t)nd * 64 + f8) = *(uint4*)o;
    }
}

extern "C" void kernel_launch(void* const* d_in, const int* in_sizes, int n_in,
                              void* d_out, int out_size, void* d_ws, size_t ws_size,
                              hipStream_t stream) {
    const void* x  = d_in[0];                        // [N][128] fp32 (or bf16)
    const int*  ei = (const int*)d_in[1];            // [2][E] int32
    const void* W1 = d_in[2];                        // [128][128]
    const void* b1 = d_in[3];                        // [128]
    const void* W2 = d_in[4];                        // [128][64]
    const void* b2 = d_in[5];                        // [64]

    const int N = in_sizes[0] / 128;
    const int E = in_sizes[1] / 2;
    const int* src = ei;
    const int* dst = ei + E;

    // bump allocator over ws (float units, 64B-aligned slots)
    float* ws = (float*)d_ws;
    size_t off = 0;
    auto alloc = [&](size_t n) { size_t p = off; off += (n + 15) & ~(size_t)15; return p; };
    int*   cnt    = (int*)(ws + alloc(64));
    int*   deg    = (int*)(ws + alloc(N));
    float* dinv   = ws + alloc(N);
    int*   offs   = (int*)(ws + alloc(N + 1));
    int*   bsum   = (int*)(ws + alloc(256));
    int*   adj    = (int*)(ws + alloc(E));
    int*   rank   = (int*)(ws + alloc(E));
    unsigned short* R1  = (unsigned short*)(ws + alloc((size_t)N * 64));  // bf16 [N][128]
    unsigned short* Hb  = (unsigned short*)(ws + alloc((size_t)N * 64));  // bf16 [N][128]
    unsigned short* Wp1 = (unsigned short*)(ws + alloc(8192));            // 16384 bf16
    unsigned short* Wp2 = (unsigned short*)(ws + alloc(4096));            // 8192 bf16
    float* b1f    = ws + alloc(128);
    float* b2f    = ws + alloc(64);
    unsigned short* H2b = Hb;  // bf16 [N][64]; Hb dead after gather1

    // zero cnt + deg (contiguous leading region)
    hipMemsetAsync(ws, 0, (64 + ((size_t)(N + 15) & ~(size_t)15)) * sizeof(float), stream);

    const int EB = (E + 1023) / 1024;   // deg_rank / scatter blocks
    const int NB = (N + 1023) / 1024;   // scan blocks (49 <= 256 required by scan23)
    const int nstrips = (N + 15) / 16;  // 3125
    const int GB = (nstrips + 3) / 4;   // gemm blocks

    // K1: degree+rank || dtype detect
    k1_deg_detect<<<EB + 1, 256, 0, stream>>>(dst, deg, rank, E,
                                              (const unsigned short*)x, cnt, EB);
    // K2: scan1(+dinv) || weight/bias prep
    k2_scan1_prep<<<NB + 13, 256, 0, stream>>>(deg, offs, bsum, dinv, N, NB,
                                               W1, W2, b1, b2, Wp1, Wp2, b1f, b2f, cnt);
    // K3: block-prefix + apply
    scan23<<<NB, 256, 0, stream>>>(bsum, offs, N, E, NB);
    // K5: edge scatter || layer-1 GEMM (dinv-scaled epilogue)
    k5_scatter_gemm1<<<EB + GB, 256, 0, stream>>>(src, dst, offs, rank, adj, E, EB,
                                                  x, Wp1, dinv, Hb, nstrips, cnt);
    // gather 1 (16 lanes/node, relu, bf16)
    gather1<<<(N + 15) / 16, 256, 0, stream>>>(Hb, dinv, b1f, offs, adj, R1, N);
    // layer-2 GEMM (dinv-scaled epilogue)
    gemm2_k<<<GB, 256, 0, stream>>>(R1, Wp2, dinv, H2b, nstrips);
    // gather 2 -> output
    gather2<<<(N + 31) / 32, 256, 0, stream>>>(H2b, dinv, b2f, offs, adj, d_out, N, cnt);
}

// Round 13
// 191.638 us; speedup vs baseline: 1.2277x; 1.0227x over previous
//
#include <hip/hip_runtime.h>

typedef __bf16 bf16x8 __attribute__((ext_vector_type(8)));
typedef float  f32x4  __attribute__((ext_vector_type(4)));

// ---------- helpers ----------
__device__ __forceinline__ float bf2f(unsigned short h) {
    return __uint_as_float(((unsigned int)h) << 16);
}
__device__ __forceinline__ unsigned short f2bf(float f) {
    unsigned int u = __float_as_uint(f);
    u += 0x7FFFu + ((u >> 16) & 1u);  // RNE
    return (unsigned short)(u >> 16);
}
__device__ __forceinline__ void unpack8(uint4 u, float* v) {
    v[0] = __uint_as_float(u.x << 16); v[1] = __uint_as_float(u.x & 0xFFFF0000u);
    v[2] = __uint_as_float(u.y << 16); v[3] = __uint_as_float(u.y & 0xFFFF0000u);
    v[4] = __uint_as_float(u.z << 16); v[5] = __uint_as_float(u.z & 0xFFFF0000u);
    v[6] = __uint_as_float(u.w << 16); v[7] = __uint_as_float(u.w & 0xFFFF0000u);
}

// ---------- K1: deg_rank (8 edges/thread) || detect (last block) ----------
__global__ void k1_deg_detect(const int* __restrict__ dst, int* __restrict__ deg,
                              int* __restrict__ rank, int E,
                              const unsigned short* __restrict__ x, int* __restrict__ cnt,
                              int degBlocks) {
    if ((int)blockIdx.x < degBlocks) {
        int base = blockIdx.x * 2048 + threadIdx.x;
#pragma unroll
        for (int k = 0; k < 8; ++k) {
            int e = base + k * 256;
            if (e < E) rank[e] = atomicAdd(&deg[dst[e]], 1);
        }
    } else {
        int c = 0;
        for (int i = threadIdx.x; i < 4096; i += 256) {
            unsigned e = (x[i] >> 7) & 0xFFu;
            if (e >= 0x88u) ++c;  // impossible for bf16 N(0,1); ~47% for fp32 low halves
        }
        if (c) atomicAdd(cnt, c);
    }
}

// ---------- weight prepack device fn ----------
// Wp[((nt*4 + ks)*64 + lane)*8 + j] = W[ks*32 + (lane>>4)*8 + j][nt*16 + (lane&15)]
template <int COLS>
__device__ __forceinline__ void prepack_one(const void* W, unsigned short* Wp, int idx,
                                            bool isf32) {
    if (idx >= (COLS / 16) * 4 * 64) return;
    int lane = idx & 63;
    int ks   = (idx >> 6) & 3;
    int nt   = idx >> 8;
    int col  = nt * 16 + (lane & 15);
    int krow = ks * 32 + (lane >> 4) * 8;
    unsigned short tmp[8];
#pragma unroll
    for (int j = 0; j < 8; ++j) {
        size_t e = (size_t)(krow + j) * COLS + col;
        float v = isf32 ? ((const float*)W)[e] : bf2f(((const unsigned short*)W)[e]);
        tmp[j] = f2bf(v);
    }
    *(uint4*)(Wp + (size_t)idx * 8) = *(uint4*)tmp;
}

// ---------- K2: scan1+dinv (blocks < NB) || prep_weights (blocks NB..NB+12) ----------
__global__ void k2_scan1_prep(const int* __restrict__ deg, int* __restrict__ offs,
                              int* __restrict__ bsum, float* __restrict__ dinv, int N, int NB,
                              const void* __restrict__ W1, const void* __restrict__ W2,
                              const void* __restrict__ b1, const void* __restrict__ b2,
                              unsigned short* __restrict__ Wp1, unsigned short* __restrict__ Wp2,
                              float* __restrict__ b1f, float* __restrict__ b2f,
                              const int* __restrict__ cnt) {
    __shared__ int s[256];
    int t = threadIdx.x;
    if ((int)blockIdx.x < NB) {
        int base = blockIdx.x * 1024 + t * 4;
        int d4[4];
#pragma unroll
        for (int k = 0; k < 4; ++k) d4[k] = (base + k < N) ? deg[base + k] : 0;
#pragma unroll
        for (int k = 0; k < 4; ++k)
            if (base + k < N) dinv[base + k] = rsqrtf((float)d4[k] + 1.0f);  // +1 self loop
        int mySum = d4[0] + d4[1] + d4[2] + d4[3];
        s[t] = mySum;
        __syncthreads();
        for (int d = 1; d < 256; d <<= 1) {
            int v = (t >= d) ? s[t - d] : 0;
            __syncthreads();
            s[t] += v;
            __syncthreads();
        }
        int run = s[t] - mySum;  // exclusive within block
#pragma unroll
        for (int k = 0; k < 4; ++k) {
            if (base + k < N) offs[base + k] = run;
            run += d4[k];
        }
        if (t == 255) bsum[blockIdx.x] = s[255];
    } else {
        bool isf32 = (*cnt >= 16);
        int bid = blockIdx.x - NB;
        if (bid < 8) {
            prepack_one<128>(W1, Wp1, bid * 256 + t, isf32);
        } else if (bid < 12) {
            prepack_one<64>(W2, Wp2, (bid - 8) * 256 + t, isf32);
        } else {
            if (t < 128) b1f[t] = isf32 ? ((const float*)b1)[t]
                                        : bf2f(((const unsigned short*)b1)[t]);
            else if (t < 192) b2f[t - 128] = isf32 ? ((const float*)b2)[t - 128]
                                                   : bf2f(((const unsigned short*)b2)[t - 128]);
        }
    }
}

// ---------- K3: scan2 recomputed per block + scan3 apply (needs NB <= 256) ----------
__global__ void scan23(const int* __restrict__ bsum, int* __restrict__ offs,
                       int N, int E, int NB) {
    __shared__ int s[256];
    int t = threadIdx.x;
    s[t] = (t < NB) ? bsum[t] : 0;
    __syncthreads();
    for (int d = 1; d < 256; d <<= 1) {
        int v = (t >= d) ? s[t - d] : 0;
        __syncthreads();
        s[t] += v;
        __syncthreads();
    }
    int boff = (blockIdx.x > 0) ? s[blockIdx.x - 1] : 0;  // exclusive prefix
    int base = blockIdx.x * 1024 + t * 4;
#pragma unroll
    for (int k = 0; k < 4; ++k) {
        int i = base + k;
        if (i < N) offs[i] += boff;
    }
    if (blockIdx.x == 0 && t == 0) offs[N] = E;
}

// ---------- layer-1 MFMA GEMM body with dinv-pre-scaled epilogue ----------
// O[row] = bf16( (X@W1)[row] * dinv[row] ), COLS=128.
// A: m=lane&15, k=(lane>>4)*8+j. C/D: col=lane&15, row=(lane>>4)*4+reg.
__device__ __forceinline__ void gemm1_body(const void* __restrict__ X,
                                           const unsigned short* __restrict__ Wp,
                                           const float* __restrict__ dinv,
                                           unsigned short* __restrict__ O, int nstrips,
                                           bool xf32, int blockI) {
    constexpr int NT = 8;
    const int wave = threadIdx.x >> 6;
    const int lane = threadIdx.x & 63;
    const int strip = blockI * 4 + wave;
    if (strip >= nstrips) return;
    const int m = lane & 15;
    const int q = lane >> 4;
    const size_t rowoff = (size_t)(strip * 16 + m) * 128 + q * 8;

    f32x4 acc[NT];
#pragma unroll
    for (int nt = 0; nt < NT; ++nt) acc[nt] = (f32x4){0.f, 0.f, 0.f, 0.f};

#pragma unroll
    for (int ks = 0; ks < 4; ++ks) {
        bf16x8 a;
        if (xf32) {
            const float* xp = (const float*)X + rowoff + ks * 32;
            float4 u = ((const float4*)xp)[0];
            float4 v = ((const float4*)xp)[1];
            unsigned short tmp[8];
            tmp[0] = f2bf(u.x); tmp[1] = f2bf(u.y); tmp[2] = f2bf(u.z); tmp[3] = f2bf(u.w);
            tmp[4] = f2bf(v.x); tmp[5] = f2bf(v.y); tmp[6] = f2bf(v.z); tmp[7] = f2bf(v.w);
            a = *(bf16x8*)tmp;
        } else {
            a = *(const bf16x8*)((const unsigned short*)X + rowoff + ks * 32);
        }
#pragma unroll
        for (int nt = 0; nt < NT; ++nt) {
            bf16x8 b = *(const bf16x8*)(Wp + (size_t)((nt * 4 + ks) * 64 + lane) * 8);
            acc[nt] = __builtin_amdgcn_mfma_f32_16x16x32_bf16(a, b, acc[nt], 0, 0, 0);
        }
    }

    const int r0 = strip * 16 + q * 4;             // multiple of 4
    float4 dv = *(const float4*)(dinv + r0);
    float dr[4] = {dv.x, dv.y, dv.z, dv.w};
#pragma unroll
    for (int nt = 0; nt < NT; ++nt) {
#pragma unroll
        for (int r = 0; r < 4; ++r)
            O[(size_t)(r0 + r) * 128 + nt * 16 + m] = f2bf(acc[nt][r] * dr[r]);
    }
}

// ---------- K5: atomic-free scatter, 8 edges/thread (blocks < SB) || gemm1 ----------
__global__ __launch_bounds__(256) void k5_scatter_gemm1(
        const int* __restrict__ src, const int* __restrict__ dst,
        const int* __restrict__ offs, const int* __restrict__ rank,
        int* __restrict__ adj, int E, int SB,
        const void* __restrict__ X, const unsigned short* __restrict__ Wp,
        const float* __restrict__ dinv,
        unsigned short* __restrict__ O, int nstrips, const int* __restrict__ cnt) {
    if ((int)blockIdx.x < SB) {
        int base = blockIdx.x * 2048 + threadIdx.x;
#pragma unroll
        for (int k = 0; k < 8; ++k) {
            int e = base + k * 256;
            if (e < E) adj[offs[dst[e]] + rank[e]] = src[e];
        }
    } else {
        gemm1_body(X, Wp, dinv, O, nstrips, (*cnt >= 16), blockIdx.x - SB);
    }
}

// ---------- FUSED gather1 + gemm2 ----------
// Phase 1: 16 lanes/node x 16 nodes gather R1 = relu(dd*(sum Hb'[s] + self) + b1)
//          into LDS (row stride 136 bf16: 16B-aligned, 2-way-max bank aliasing on reads).
// Phase 2: wave w computes the 16x16 output tile nt=w of H2b' = (R1 @ W2)*dinv via MFMA,
//          A-fragments straight from LDS. R1 never touches global memory.
__global__ __launch_bounds__(256) void gather1_gemm2(
        const unsigned short* __restrict__ Hb, const float* __restrict__ dinv,
        const float* __restrict__ b, const int* __restrict__ offs,
        const int* __restrict__ adj, const unsigned short* __restrict__ Wp2,
        unsigned short* __restrict__ H2b, int N) {
    __shared__ unsigned short Rs[16][136];
    const int strip = blockIdx.x;
    const int lane = threadIdx.x & 63;

    // ---- phase 1: gather ----
    {
        int ndl = threadIdx.x >> 4;        // local node 0..15
        int nd = strip * 16 + ndl;
        int l15 = lane & 15;
        int gbase = lane & ~15;
        int f8 = l15 * 8;
        if (nd < N) {
            float acc[8];
#pragma unroll
            for (int k = 0; k < 8; ++k) acc[k] = 0.f;
            int beg = offs[nd], end = offs[nd + 1];
            for (int c = beg; c < end; c += 16) {
                int rem = end - c;  // >= 1
                int myadj = (l15 < rem) ? adj[c + l15] : 0;  // dummy row 0, weight 0
#pragma unroll
                for (int t = 0; t < 16; t += 8) {
                    if (t >= rem) break;
                    int sI[8];
#pragma unroll
                    for (int k = 0; k < 8; ++k) sI[k] = __shfl(myadj, gbase + t + k, 64);
                    uint4 u[8];
#pragma unroll
                    for (int k = 0; k < 8; ++k)
                        u[k] = *(const uint4*)(Hb + (size_t)sI[k] * 128 + f8);
                    float n[8];
#pragma unroll
                    for (int k = 0; k < 8; ++k) n[k] = (t + k < rem) ? 1.f : 0.f;
#pragma unroll
                    for (int k = 0; k < 8; ++k) {
                        float v[8];
                        unpack8(u[k], v);
#pragma unroll
                        for (int j = 0; j < 8; ++j) acc[j] = fmaf(v[j], n[k], acc[j]);
                    }
                }
            }
            float dd = dinv[nd];
            float hv[8], bb[8];
            unpack8(*(const uint4*)(Hb + (size_t)nd * 128 + f8), hv);  // self (pre-scaled)
            *(float4*)&bb[0] = *(const float4*)(b + f8);
            *(float4*)&bb[4] = *(const float4*)(b + f8 + 4);
            unsigned short o[8];
#pragma unroll
            for (int k = 0; k < 8; ++k) {
                float a = fmaf(acc[k] + hv[k], dd, bb[k]);
                o[k] = f2bf(fmaxf(a, 0.f));
            }
            *(uint4*)&Rs[ndl][f8] = *(uint4*)o;
        } else {
            uint4 z = make_uint4(0, 0, 0, 0);
            *(uint4*)&Rs[ndl][f8] = z;
        }
    }
    __syncthreads();

    // ---- phase 2: 16x64 GEMM, wave = col-tile ----
    {
        const int nt = threadIdx.x >> 6;   // 0..3
        const int m = lane & 15;
        const int q = lane >> 4;
        f32x4 acc = (f32x4){0.f, 0.f, 0.f, 0.f};
#pragma unroll
        for (int ks = 0; ks < 4; ++ks) {
            bf16x8 a = *(const bf16x8*)&Rs[m][ks * 32 + q * 8];
            bf16x8 bfr = *(const bf16x8*)(Wp2 + (size_t)((nt * 4 + ks) * 64 + lane) * 8);
            acc = __builtin_amdgcn_mfma_f32_16x16x32_bf16(a, bfr, acc, 0, 0, 0);
        }
        const int r0 = strip * 16 + q * 4;
#pragma unroll
        for (int r = 0; r < 4; ++r) {
            int row = r0 + r;
            if (row < N)
                H2b[(size_t)row * 64 + nt * 16 + m] = f2bf(acc[r] * dinv[row]);
        }
    }
}

// ---------- gather layer 2: out = dd*(sum H2b'[s] + H2b'[nd]) + b ----------
// 8 lanes/node, 32 nodes/block; adj batched 8/chunk, straight-line 8-way body.
__global__ void gather2(const unsigned short* __restrict__ H2b, const float* __restrict__ dinv,
                        const float* __restrict__ b, const int* __restrict__ offs,
                        const int* __restrict__ adj, void* __restrict__ out,
                        int N, const int* __restrict__ cnt) {
    bool isf32 = (*cnt >= 16);
    int nd = blockIdx.x * 32 + (threadIdx.x >> 3);
    int lane = threadIdx.x & 63;
    int l7 = lane & 7;
    int gbase = lane & ~7;
    int f8 = l7 * 8;
    if (nd >= N) return;

    float acc[8];
#pragma unroll
    for (int k = 0; k < 8; ++k) acc[k] = 0.f;

    int beg = offs[nd], end = offs[nd + 1];
    for (int c = beg; c < end; c += 8) {
        int rem = end - c;
        int myadj = (l7 < rem) ? adj[c + l7] : 0;
        int sI[8];
#pragma unroll
        for (int k = 0; k < 8; ++k) sI[k] = __shfl(myadj, gbase + k, 64);
        uint4 u[8];
#pragma unroll
        for (int k = 0; k < 8; ++k) u[k] = *(const uint4*)(H2b + (size_t)sI[k] * 64 + f8);
        float n[8];
#pragma unroll
        for (int k = 0; k < 8; ++k) n[k] = (k < rem) ? 1.f : 0.f;
#pragma unroll
        for (int k = 0; k < 8; ++k) {
            float v[8];
            unpack8(u[k], v);
#pragma unroll
            for (int j = 0; j < 8; ++j) acc[j] = fmaf(v[j], n[k], acc[j]);
        }
    }
    float dd = dinv[nd];
    float hv[8], bb[8];
    unpack8(*(const uint4*)(H2b + (size_t)nd * 64 + f8), hv);
    *(float4*)&bb[0] = *(const float4*)(b + f8);
    *(float4*)&bb[4] = *(const float4*)(b + f8 + 4);
    float r[8];
#pragma unroll
    for (int k = 0; k < 8; ++k) r[k] = fmaf(acc[k] + hv[k], dd, bb[k]);
    if (isf32) {
        float* op = (float*)out + (size_t)nd * 64 + f8;
        *(float4*)op       = *(float4*)&r[0];
        *(float4*)(op + 4) = *(float4*)&r[4];
    } else {
        unsigned short o[8];
#pragma unroll
        for (int k = 0; k < 8; ++k) o[k] = f2bf(r[k]);
        *(uint4*)((unsigned short*)out + (size_t)nd * 64 + f8) = *(uint4*)o;
    }
}

extern "C" void kernel_launch(void* const* d_in, const int* in_sizes, int n_in,
                              void* d_out, int out_size, void* d_ws, size_t ws_size,
                              hipStream_t stream) {
    const void* x  = d_in[0];                        // [N][128] fp32 (or bf16)
    const int*  ei = (const int*)d_in[1];            // [2][E] int32
    const void* W1 = d_in[2];                        // [128][128]
    const void* b1 = d_in[3];                        // [128]
    const void* W2 = d_in[4];                        // [128][64]
    const void* b2 = d_in[5];                        // [64]

    const int N = in_sizes[0] / 128;
    const int E = in_sizes[1] / 2;
    const int* src = ei;
    const int* dst = ei + E;

    // bump allocator over ws (float units, 64B-aligned slots)
    float* ws = (float*)d_ws;
    size_t off = 0;
    auto alloc = [&](size_t n) { size_t p = off; off += (n + 15) & ~(size_t)15; return p; };
    int*   cnt    = (int*)(ws + alloc(64));
    int*   deg    = (int*)(ws + alloc(N));
    float* dinv   = ws + alloc(N);
    int*   offs   = (int*)(ws + alloc(N + 1));
    int*   bsum   = (int*)(ws + alloc(256));
    int*   adj    = (int*)(ws + alloc(E));
    int*   rank   = (int*)(ws + alloc(E));
    unsigned short* Hb  = (unsigned short*)(ws + alloc((size_t)N * 64));  // bf16 [N][128]
    unsigned short* Wp1 = (unsigned short*)(ws + alloc(8192));            // 16384 bf16
    unsigned short* Wp2 = (unsigned short*)(ws + alloc(4096));            // 8192 bf16
    float* b1f    = ws + alloc(128);
    float* b2f    = ws + alloc(64);
    unsigned short* H2b = (unsigned short*)(ws + alloc((size_t)N * 32)); // bf16 [N][64]

    // zero cnt + deg (contiguous leading region)
    hipMemsetAsync(ws, 0, (64 + ((size_t)(N + 15) & ~(size_t)15)) * sizeof(float), stream);

    const int EB8 = (E + 2047) / 2048;  // deg_rank / scatter blocks (8 edges/thread)
    const int NB = (N + 1023) / 1024;   // scan blocks (49 <= 256 required by scan23)
    const int nstrips = (N + 15) / 16;  // 3125
    const int GB = (nstrips + 3) / 4;   // gemm1 blocks

    // K1: degree+rank || dtype detect
    k1_deg_detect<<<EB8 + 1, 256, 0, stream>>>(dst, deg, rank, E,
                                               (const unsigned short*)x, cnt, EB8);
    // K2: scan1(+dinv) || weight/bias prep
    k2_scan1_prep<<<NB + 13, 256, 0, stream>>>(deg, offs, bsum, dinv, N, NB,
                                               W1, W2, b1, b2, Wp1, Wp2, b1f, b2f, cnt);
    // K3: block-prefix + apply
    scan23<<<NB, 256, 0, stream>>>(bsum, offs, N, E, NB);
    // K5: edge scatter || layer-1 GEMM (dinv-scaled epilogue)
    k5_scatter_gemm1<<<EB8 + GB, 256, 0, stream>>>(src, dst, offs, rank, adj, E, EB8,
                                                   x, Wp1, dinv, Hb, nstrips, cnt);
    // FUSED gather1 (LDS R1) + gemm2 (dinv-scaled epilogue)
    gather1_gemm2<<<nstrips, 256, 0, stream>>>(Hb, dinv, b1f, offs, adj, Wp2, H2b, N);
    // gather 2 -> output
    gather2<<<(N + 31) / 32, 256, 0, stream>>>(H2b, dinv, b2f, offs, adj, d_out, N, cnt);
}

// Round 14
// 187.579 us; speedup vs baseline: 1.2542x; 1.0216x over previous
//
#include <hip/hip_runtime.h>

typedef __bf16 bf16x8 __attribute__((ext_vector_type(8)));
typedef float  f32x4  __attribute__((ext_vector_type(4)));

// ---------- helpers ----------
__device__ __forceinline__ float bf2f(unsigned short h) {
    return __uint_as_float(((unsigned int)h) << 16);
}
__device__ __forceinline__ unsigned short f2bf(float f) {
    unsigned int u = __float_as_uint(f);
    u += 0x7FFFu + ((u >> 16) & 1u);  // RNE
    return (unsigned short)(u >> 16);
}
__device__ __forceinline__ void unpack8(uint4 u, float* v) {
    v[0] = __uint_as_float(u.x << 16); v[1] = __uint_as_float(u.x & 0xFFFF0000u);
    v[2] = __uint_as_float(u.y << 16); v[3] = __uint_as_float(u.y & 0xFFFF0000u);
    v[4] = __uint_as_float(u.z << 16); v[5] = __uint_as_float(u.z & 0xFFFF0000u);
    v[6] = __uint_as_float(u.w << 16); v[7] = __uint_as_float(u.w & 0xFFFF0000u);
}

// ---------- K1: deg_rank (8 contiguous edges/thread, int4 loads) || detect ----------
__global__ void k1_deg_detect(const int* __restrict__ dst, int* __restrict__ deg,
                              int* __restrict__ rank, int E,
                              const unsigned short* __restrict__ x, int* __restrict__ cnt,
                              int degBlocks) {
    if ((int)blockIdx.x < degBlocks) {
        int e0 = (blockIdx.x * 256 + threadIdx.x) * 8;
        if (e0 + 8 <= E) {
            int4 d0 = *(const int4*)(dst + e0);
            int4 d1 = *(const int4*)(dst + e0 + 4);
            int r[8];
            r[0] = atomicAdd(&deg[d0.x], 1); r[1] = atomicAdd(&deg[d0.y], 1);
            r[2] = atomicAdd(&deg[d0.z], 1); r[3] = atomicAdd(&deg[d0.w], 1);
            r[4] = atomicAdd(&deg[d1.x], 1); r[5] = atomicAdd(&deg[d1.y], 1);
            r[6] = atomicAdd(&deg[d1.z], 1); r[7] = atomicAdd(&deg[d1.w], 1);
            *(int4*)(rank + e0)     = make_int4(r[0], r[1], r[2], r[3]);
            *(int4*)(rank + e0 + 4) = make_int4(r[4], r[5], r[6], r[7]);
        } else {
            for (int e = e0; e < E; ++e) rank[e] = atomicAdd(&deg[dst[e]], 1);
        }
    } else {
        int c = 0;
        for (int i = threadIdx.x; i < 4096; i += 256) {
            unsigned e = (x[i] >> 7) & 0xFFu;
            if (e >= 0x88u) ++c;  // impossible for bf16 N(0,1); ~47% for fp32 low halves
        }
        if (c) atomicAdd(cnt, c);
    }
}

// ---------- weight prepack device fn ----------
// Wp[((nt*4 + ks)*64 + lane)*8 + j] = W[ks*32 + (lane>>4)*8 + j][nt*16 + (lane&15)]
template <int COLS>
__device__ __forceinline__ void prepack_one(const void* W, unsigned short* Wp, int idx,
                                            bool isf32) {
    if (idx >= (COLS / 16) * 4 * 64) return;
    int lane = idx & 63;
    int ks   = (idx >> 6) & 3;
    int nt   = idx >> 8;
    int col  = nt * 16 + (lane & 15);
    int krow = ks * 32 + (lane >> 4) * 8;
    unsigned short tmp[8];
#pragma unroll
    for (int j = 0; j < 8; ++j) {
        size_t e = (size_t)(krow + j) * COLS + col;
        float v = isf32 ? ((const float*)W)[e] : bf2f(((const unsigned short*)W)[e]);
        tmp[j] = f2bf(v);
    }
    *(uint4*)(Wp + (size_t)idx * 8) = *(uint4*)tmp;
}

// ---------- K2: scan1+dinv (blocks < NB) || prep_weights (blocks NB..NB+12) ----------
__global__ void k2_scan1_prep(const int* __restrict__ deg, int* __restrict__ offs,
                              int* __restrict__ bsum, float* __restrict__ dinv, int N, int NB,
                              const void* __restrict__ W1, const void* __restrict__ W2,
                              const void* __restrict__ b1, const void* __restrict__ b2,
                              unsigned short* __restrict__ Wp1, unsigned short* __restrict__ Wp2,
                              float* __restrict__ b1f, float* __restrict__ b2f,
                              const int* __restrict__ cnt) {
    __shared__ int s[256];
    int t = threadIdx.x;
    if ((int)blockIdx.x < NB) {
        int base = blockIdx.x * 1024 + t * 4;
        int d4[4];
#pragma unroll
        for (int k = 0; k < 4; ++k) d4[k] = (base + k < N) ? deg[base + k] : 0;
#pragma unroll
        for (int k = 0; k < 4; ++k)
            if (base + k < N) dinv[base + k] = rsqrtf((float)d4[k] + 1.0f);  // +1 self loop
        int mySum = d4[0] + d4[1] + d4[2] + d4[3];
        s[t] = mySum;
        __syncthreads();
        for (int d = 1; d < 256; d <<= 1) {
            int v = (t >= d) ? s[t - d] : 0;
            __syncthreads();
            s[t] += v;
            __syncthreads();
        }
        int run = s[t] - mySum;  // exclusive within block
#pragma unroll
        for (int k = 0; k < 4; ++k) {
            if (base + k < N) offs[base + k] = run;
            run += d4[k];
        }
        if (t == 255) bsum[blockIdx.x] = s[255];
    } else {
        bool isf32 = (*cnt >= 16);
        int bid = blockIdx.x - NB;
        if (bid < 8) {
            prepack_one<128>(W1, Wp1, bid * 256 + t, isf32);
        } else if (bid < 12) {
            prepack_one<64>(W2, Wp2, (bid - 8) * 256 + t, isf32);
        } else {
            if (t < 128) b1f[t] = isf32 ? ((const float*)b1)[t]
                                        : bf2f(((const unsigned short*)b1)[t]);
            else if (t < 192) b2f[t - 128] = isf32 ? ((const float*)b2)[t - 128]
                                                   : bf2f(((const unsigned short*)b2)[t - 128]);
        }
    }
}

// ---------- K3: scan2 recomputed per block + scan3 apply (needs NB <= 256) ----------
__global__ void scan23(const int* __restrict__ bsum, int* __restrict__ offs,
                       int N, int E, int NB) {
    __shared__ int s[256];
    int t = threadIdx.x;
    s[t] = (t < NB) ? bsum[t] : 0;
    __syncthreads();
    for (int d = 1; d < 256; d <<= 1) {
        int v = (t >= d) ? s[t - d] : 0;
        __syncthreads();
        s[t] += v;
        __syncthreads();
    }
    int boff = (blockIdx.x > 0) ? s[blockIdx.x - 1] : 0;  // exclusive prefix
    int base = blockIdx.x * 1024 + t * 4;
#pragma unroll
    for (int k = 0; k < 4; ++k) {
        int i = base + k;
        if (i < N) offs[i] += boff;
    }
    if (blockIdx.x == 0 && t == 0) offs[N] = E;
}

// ---------- layer-1 MFMA GEMM body with dinv-pre-scaled epilogue ----------
// O[row] = bf16( (X@W1)[row] * dinv[row] ), COLS=128.
// A: m=lane&15, k=(lane>>4)*8+j. C/D: col=lane&15, row=(lane>>4)*4+reg.
__device__ __forceinline__ void gemm1_body(const void* __restrict__ X,
                                           const unsigned short* __restrict__ Wp,
                                           const float* __restrict__ dinv,
                                           unsigned short* __restrict__ O, int nstrips,
                                           bool xf32, int blockI) {
    constexpr int NT = 8;
    const int wave = threadIdx.x >> 6;
    const int lane = threadIdx.x & 63;
    const int strip = blockI * 4 + wave;
    if (strip >= nstrips) return;
    const int m = lane & 15;
    const int q = lane >> 4;
    const size_t rowoff = (size_t)(strip * 16 + m) * 128 + q * 8;

    f32x4 acc[NT];
#pragma unroll
    for (int nt = 0; nt < NT; ++nt) acc[nt] = (f32x4){0.f, 0.f, 0.f, 0.f};

#pragma unroll
    for (int ks = 0; ks < 4; ++ks) {
        bf16x8 a;
        if (xf32) {
            const float* xp = (const float*)X + rowoff + ks * 32;
            float4 u = ((const float4*)xp)[0];
            float4 v = ((const float4*)xp)[1];
            unsigned short tmp[8];
            tmp[0] = f2bf(u.x); tmp[1] = f2bf(u.y); tmp[2] = f2bf(u.z); tmp[3] = f2bf(u.w);
            tmp[4] = f2bf(v.x); tmp[5] = f2bf(v.y); tmp[6] = f2bf(v.z); tmp[7] = f2bf(v.w);
            a = *(bf16x8*)tmp;
        } else {
            a = *(const bf16x8*)((const unsigned short*)X + rowoff + ks * 32);
        }
#pragma unroll
        for (int nt = 0; nt < NT; ++nt) {
            bf16x8 b = *(const bf16x8*)(Wp + (size_t)((nt * 4 + ks) * 64 + lane) * 8);
            acc[nt] = __builtin_amdgcn_mfma_f32_16x16x32_bf16(a, b, acc[nt], 0, 0, 0);
        }
    }

    const int r0 = strip * 16 + q * 4;             // multiple of 4
    float4 dv = *(const float4*)(dinv + r0);
    float dr[4] = {dv.x, dv.y, dv.z, dv.w};
#pragma unroll
    for (int nt = 0; nt < NT; ++nt) {
#pragma unroll
        for (int r = 0; r < 4; ++r)
            O[(size_t)(r0 + r) * 128 + nt * 16 + m] = f2bf(acc[nt][r] * dr[r]);
    }
}

// ---------- K5: atomic-free scatter (8 contiguous edges/thread) || gemm1 ----------
__global__ __launch_bounds__(256) void k5_scatter_gemm1(
        const int* __restrict__ src, const int* __restrict__ dst,
        const int* __restrict__ offs, const int* __restrict__ rank,
        int* __restrict__ adj, int E, int SB,
        const void* __restrict__ X, const unsigned short* __restrict__ Wp,
        const float* __restrict__ dinv,
        unsigned short* __restrict__ O, int nstrips, const int* __restrict__ cnt) {
    if ((int)blockIdx.x < SB) {
        int e0 = (blockIdx.x * 256 + threadIdx.x) * 8;
        if (e0 + 8 <= E) {
            int4 d0 = *(const int4*)(dst + e0);
            int4 d1 = *(const int4*)(dst + e0 + 4);
            int4 s0 = *(const int4*)(src + e0);
            int4 s1 = *(const int4*)(src + e0 + 4);
            int4 r0 = *(const int4*)(rank + e0);
            int4 r1 = *(const int4*)(rank + e0 + 4);
            adj[offs[d0.x] + r0.x] = s0.x;
            adj[offs[d0.y] + r0.y] = s0.y;
            adj[offs[d0.z] + r0.z] = s0.z;
            adj[offs[d0.w] + r0.w] = s0.w;
            adj[offs[d1.x] + r1.x] = s1.x;
            adj[offs[d1.y] + r1.y] = s1.y;
            adj[offs[d1.z] + r1.z] = s1.z;
            adj[offs[d1.w] + r1.w] = s1.w;
        } else {
            for (int e = e0; e < E; ++e) adj[offs[dst[e]] + rank[e]] = src[e];
        }
    } else {
        gemm1_body(X, Wp, dinv, O, nstrips, (*cnt >= 16), blockIdx.x - SB);
    }
}

// ---------- FUSED gather1 + gemm2 ----------
// Phase 1: 16 lanes/node x 16 nodes gather R1 = relu(dd*(sum Hb'[s] + self) + b1)
//          into LDS (row stride 136 bf16). Phase 2: wave nt computes the 16x16 tile
//          of H2b' = (R1 @ W2)*dinv via MFMA from LDS. R1 never hits global memory.
__global__ __launch_bounds__(256) void gather1_gemm2(
        const unsigned short* __restrict__ Hb, const float* __restrict__ dinv,
        const float* __restrict__ b, const int* __restrict__ offs,
        const int* __restrict__ adj, const unsigned short* __restrict__ Wp2,
        unsigned short* __restrict__ H2b, int N) {
    __shared__ unsigned short Rs[16][136];
    const int strip = blockIdx.x;
    const int lane = threadIdx.x & 63;

    // ---- phase 1: gather ----
    {
        int ndl = threadIdx.x >> 4;        // local node 0..15
        int nd = strip * 16 + ndl;
        int l15 = lane & 15;
        int gbase = lane & ~15;
        int f8 = l15 * 8;
        if (nd < N) {
            float acc[8];
#pragma unroll
            for (int k = 0; k < 8; ++k) acc[k] = 0.f;
            int beg = offs[nd], end = offs[nd + 1];
            for (int c = beg; c < end; c += 16) {
                int rem = end - c;  // >= 1
                int myadj = (l15 < rem) ? adj[c + l15] : 0;  // dummy row 0, weight 0
#pragma unroll
                for (int t = 0; t < 16; t += 8) {
                    if (t >= rem) break;
                    int sI[8];
#pragma unroll
                    for (int k = 0; k < 8; ++k) sI[k] = __shfl(myadj, gbase + t + k, 64);
                    uint4 u[8];
#pragma unroll
                    for (int k = 0; k < 8; ++k)
                        u[k] = *(const uint4*)(Hb + (size_t)sI[k] * 128 + f8);
                    float n[8];
#pragma unroll
                    for (int k = 0; k < 8; ++k) n[k] = (t + k < rem) ? 1.f : 0.f;
#pragma unroll
                    for (int k = 0; k < 8; ++k) {
                        float v[8];
                        unpack8(u[k], v);
#pragma unroll
                        for (int j = 0; j < 8; ++j) acc[j] = fmaf(v[j], n[k], acc[j]);
                    }
                }
            }
            float dd = dinv[nd];
            float hv[8], bb[8];
            unpack8(*(const uint4*)(Hb + (size_t)nd * 128 + f8), hv);  // self (pre-scaled)
            *(float4*)&bb[0] = *(const float4*)(b + f8);
            *(float4*)&bb[4] = *(const float4*)(b + f8 + 4);
            unsigned short o[8];
#pragma unroll
            for (int k = 0; k < 8; ++k) {
                float a = fmaf(acc[k] + hv[k], dd, bb[k]);
                o[k] = f2bf(fmaxf(a, 0.f));
            }
            *(uint4*)&Rs[ndl][f8] = *(uint4*)o;
        } else {
            uint4 z = make_uint4(0, 0, 0, 0);
            *(uint4*)&Rs[ndl][f8] = z;
        }
    }
    __syncthreads();

    // ---- phase 2: 16x64 GEMM, wave = col-tile ----
    {
        const int nt = threadIdx.x >> 6;   // 0..3
        const int m = lane & 15;
        const int q = lane >> 4;
        f32x4 acc = (f32x4){0.f, 0.f, 0.f, 0.f};
#pragma unroll
        for (int ks = 0; ks < 4; ++ks) {
            bf16x8 a = *(const bf16x8*)&Rs[m][ks * 32 + q * 8];
            bf16x8 bfr = *(const bf16x8*)(Wp2 + (size_t)((nt * 4 + ks) * 64 + lane) * 8);
            acc = __builtin_amdgcn_mfma_f32_16x16x32_bf16(a, bfr, acc, 0, 0, 0);
        }
        const int r0 = strip * 16 + q * 4;  // multiple of 4
        if (r0 + 3 < N) {
            float4 dv = *(const float4*)(dinv + r0);
            float dr[4] = {dv.x, dv.y, dv.z, dv.w};
#pragma unroll
            for (int r = 0; r < 4; ++r)
                H2b[(size_t)(r0 + r) * 64 + nt * 16 + m] = f2bf(acc[r] * dr[r]);
        } else {
#pragma unroll
            for (int r = 0; r < 4; ++r) {
                int row = r0 + r;
                if (row < N)
                    H2b[(size_t)row * 64 + nt * 16 + m] = f2bf(acc[r] * dinv[row]);
            }
        }
    }
}

// ---------- gather layer 2: out = dd*(sum H2b'[s] + H2b'[nd]) + b ----------
// 8 lanes/node, 32 nodes/block; adj batched 8/chunk, straight-line 8-way body.
__global__ void gather2(const unsigned short* __restrict__ H2b, const float* __restrict__ dinv,
                        const float* __restrict__ b, const int* __restrict__ offs,
                        const int* __restrict__ adj, void* __restrict__ out,
                        int N, const int* __restrict__ cnt) {
    bool isf32 = (*cnt >= 16);
    int nd = blockIdx.x * 32 + (threadIdx.x >> 3);
    int lane = threadIdx.x & 63;
    int l7 = lane & 7;
    int gbase = lane & ~7;
    int f8 = l7 * 8;
    if (nd >= N) return;

    float acc[8];
#pragma unroll
    for (int k = 0; k < 8; ++k) acc[k] = 0.f;

    int beg = offs[nd], end = offs[nd + 1];
    for (int c = beg; c < end; c += 8) {
        int rem = end - c;
        int myadj = (l7 < rem) ? adj[c + l7] : 0;
        int sI[8];
#pragma unroll
        for (int k = 0; k < 8; ++k) sI[k] = __shfl(myadj, gbase + k, 64);
        uint4 u[8];
#pragma unroll
        for (int k = 0; k < 8; ++k) u[k] = *(const uint4*)(H2b + (size_t)sI[k] * 64 + f8);
        float n[8];
#pragma unroll
        for (int k = 0; k < 8; ++k) n[k] = (k < rem) ? 1.f : 0.f;
#pragma unroll
        for (int k = 0; k < 8; ++k) {
            float v[8];
            unpack8(u[k], v);
#pragma unroll
            for (int j = 0; j < 8; ++j) acc[j] = fmaf(v[j], n[k], acc[j]);
        }
    }
    float dd = dinv[nd];
    float hv[8], bb[8];
    unpack8(*(const uint4*)(H2b + (size_t)nd * 64 + f8), hv);
    *(float4*)&bb[0] = *(const float4*)(b + f8);
    *(float4*)&bb[4] = *(const float4*)(b + f8 + 4);
    float r[8];
#pragma unroll
    for (int k = 0; k < 8; ++k) r[k] = fmaf(acc[k] + hv[k], dd, bb[k]);
    if (isf32) {
        float* op = (float*)out + (size_t)nd * 64 + f8;
        *(float4*)op       = *(float4*)&r[0];
        *(float4*)(op + 4) = *(float4*)&r[4];
    } else {
        unsigned short o[8];
#pragma unroll
        for (int k = 0; k < 8; ++k) o[k] = f2bf(r[k]);
        *(uint4*)((unsigned short*)out + (size_t)nd * 64 + f8) = *(uint4*)o;
    }
}

extern "C" void kernel_launch(void* const* d_in, const int* in_sizes, int n_in,
                              void* d_out, int out_size, void* d_ws, size_t ws_size,
                              hipStream_t stream) {
    const void* x  = d_in[0];                        // [N][128] fp32 (or bf16)
    const int*  ei = (const int*)d_in[1];            // [2][E] int32
    const void* W1 = d_in[2];                        // [128][128]
    const void* b1 = d_in[3];                        // [128]
    const void* W2 = d_in[4];                        // [128][64]
    const void* b2 = d_in[5];                        // [64]

    const int N = in_sizes[0] / 128;
    const int E = in_sizes[1] / 2;
    const int* src = ei;
    const int* dst = ei + E;

    // bump allocator over ws (float units, 64B-aligned slots)
    float* ws = (float*)d_ws;
    size_t off = 0;
    auto alloc = [&](size_t n) { size_t p = off; off += (n + 15) & ~(size_t)15; return p; };
    int*   cnt    = (int*)(ws + alloc(64));
    int*   deg    = (int*)(ws + alloc(N));
    float* dinv   = ws + alloc(N);
    int*   offs   = (int*)(ws + alloc(N + 1));
    int*   bsum   = (int*)(ws + alloc(256));
    int*   adj    = (int*)(ws + alloc(E));
    int*   rank   = (int*)(ws + alloc(E));
    unsigned short* Hb  = (unsigned short*)(ws + alloc((size_t)N * 64));  // bf16 [N][128]
    unsigned short* Wp1 = (unsigned short*)(ws + alloc(8192));            // 16384 bf16
    unsigned short* Wp2 = (unsigned short*)(ws + alloc(4096));            // 8192 bf16
    float* b1f    = ws + alloc(128);
    float* b2f    = ws + alloc(64);
    unsigned short* H2b = (unsigned short*)(ws + alloc((size_t)N * 32)); // bf16 [N][64]

    // zero cnt + deg (contiguous leading region)
    hipMemsetAsync(ws, 0, (64 + ((size_t)(N + 15) & ~(size_t)15)) * sizeof(float), stream);

    const int EB8 = (E + 2047) / 2048;  // 8 edges/thread blocks
    const int NB = (N + 1023) / 1024;   // scan blocks (49 <= 256 required by scan23)
    const int nstrips = (N + 15) / 16;  // 3125
    const int GB = (nstrips + 3) / 4;   // gemm1 blocks

    // K1: degree+rank || dtype detect
    k1_deg_detect<<<EB8 + 1, 256, 0, stream>>>(dst, deg, rank, E,
                                               (const unsigned short*)x, cnt, EB8);
    // K2: scan1(+dinv) || weight/bias prep
    k2_scan1_prep<<<NB + 13, 256, 0, stream>>>(deg, offs, bsum, dinv, N, NB,
                                               W1, W2, b1, b2, Wp1, Wp2, b1f, b2f, cnt);
    // K3: block-prefix + apply
    scan23<<<NB, 256, 0, stream>>>(bsum, offs, N, E, NB);
    // K5: edge scatter || layer-1 GEMM (dinv-scaled epilogue)
    k5_scatter_gemm1<<<EB8 + GB, 256, 0, stream>>>(src, dst, offs, rank, adj, E, EB8,
                                                   x, Wp1, dinv, Hb, nstrips, cnt);
    // FUSED gather1 (LDS R1) + gemm2 (dinv-scaled epilogue)
    gather1_gemm2<<<nstrips, 256, 0, stream>>>(Hb, dinv, b1f, offs, adj, Wp2, H2b, N);
    // gather 2 -> output
    gather2<<<(N + 31) / 32, 256, 0, stream>>>(H2b, dinv, b2f, offs, adj, d_out, N, cnt);
}